// Round 9
// baseline (433.763 us; speedup 1.0000x reference)
//
#include <hip/hip_runtime.h>
#include <cstdint>

// GAT 2-layer: N=50000, E=800000.
// Layer 1 via linearity: aggregate x (256B bf16 rows, L2-resident), then
// batched per-head MFMA GEMM. Agg kernels: 4 edges in flight per wave
// (4 groups x 16 lanes) to cut the serial gather chain 4x.
#define NN 50000
#define NE 800000

typedef short bf16x8 __attribute__((ext_vector_type(8)));
typedef float f32x4 __attribute__((ext_vector_type(4)));

__device__ __forceinline__ float lrelu(float x) { return x > 0.f ? x : 0.2f * x; }
__device__ __forceinline__ float elu(float x) { return x > 0.f ? x : __expf(x) - 1.f; }
__device__ __forceinline__ unsigned short f2bf(float f) {
  unsigned u = __float_as_uint(f);
  unsigned r = (u + 0x7FFFu + ((u >> 16) & 1u)) >> 16;   // RNE
  return (unsigned short)r;
}

// ===================== prep =====================
__global__ __launch_bounds__(256)
void cvt_x_kernel(const float* __restrict__ in, unsigned short* __restrict__ outb) {
  int idx = blockIdx.x * 256 + threadIdx.x;      // 8 elems each
  if (idx >= NN * 128 / 8) return;
  float4 a = *(const float4*)(in + (size_t)idx * 8);
  float4 b = *(const float4*)(in + (size_t)idx * 8 + 4);
  unsigned short us[8] = { f2bf(a.x), f2bf(a.y), f2bf(a.z), f2bf(a.w),
                           f2bf(b.x), f2bf(b.y), f2bf(b.z), f2bf(b.w) };
  *(uint4*)(outb + (size_t)idx * 8) = *(const uint4*)us;
}

// W [K][N] f32 -> WT [N][K] bf16
template<int K, int N>
__global__ __launch_bounds__(256)
void cvt_wt_kernel(const float* __restrict__ w, unsigned short* __restrict__ wt) {
  int idx = blockIdx.x * 256 + threadIdx.x;
  if (idx >= K * N) return;
  int k = idx / N, c = idx % N;
  wt[(size_t)c * K + k] = f2bf(w[idx]);
}

// walb[o][k] (o: 0-7 el heads, 8-15 er heads) = sum_d W1[k, h*64+d]*a[h,d]
__global__ __launch_bounds__(256)
void wal_kernel(const float* __restrict__ W1, const float* __restrict__ al,
                const float* __restrict__ ar, unsigned short* __restrict__ walb) {
  int idx = blockIdx.x * 256 + threadIdx.x;   // 2048 total
  if (idx >= 2048) return;
  int k = idx >> 4, o = idx & 15, h = o & 7;
  const float* a = (o < 8) ? al : ar;
  float s = 0.f;
  #pragma unroll 8
  for (int d = 0; d < 64; ++d)
    s += W1[(size_t)k * 512 + h * 64 + d] * a[h * 64 + d];
  walb[o * 128 + k] = f2bf(s);
}

// ===== eler: el1/er1 [N,8] = xb @ walb^T via MFMA, 16 nodes/wave ============
__global__ __launch_bounds__(256)
void eler_kernel(const unsigned short* __restrict__ xb,    // [NN][128]
                 const unsigned short* __restrict__ walb,  // [16][128]
                 float* __restrict__ el, float* __restrict__ er) {
  int wv = threadIdx.x >> 6, lane = threadIdx.x & 63;
  int row0 = blockIdx.x * 64 + wv * 16;
  const int l15 = lane & 15, kg = lane >> 4;
  f32x4 c = {0.f, 0.f, 0.f, 0.f};
  #pragma unroll
  for (int ks = 0; ks < 4; ++ks) {
    bf16x8 a = {};
    int row = row0 + l15;
    if (row < NN) a = *(const bf16x8*)(xb + (size_t)row * 128 + ks * 32 + kg * 8);
    bf16x8 b = *(const bf16x8*)(walb + (size_t)l15 * 128 + ks * 32 + kg * 8);
    c = __builtin_amdgcn_mfma_f32_16x16x32_bf16(a, b, c, 0, 0, 0);
  }
  #pragma unroll
  for (int r = 0; r < 4; ++r) {
    int row = row0 + kg * 4 + r;
    if (row < NN) {
      if (l15 < 8) el[(size_t)row * 8 + l15] = c[r];
      else         er[(size_t)row * 8 + (l15 - 8)] = c[r];
    }
  }
}

// ===================== CSR build (by dst) ====================================
__global__ void hist_kernel(const int* __restrict__ dst, int* __restrict__ cnt, int E) {
  int e = blockIdx.x * 256 + threadIdx.x;
  if (e < E) atomicAdd(&cnt[dst[e]], 1);
}

__global__ __launch_bounds__(1024)
void scan_kernel(const int* __restrict__ cnt, int* __restrict__ rowptr, int N) {
  __shared__ int sums[1024];
  int t = threadIdx.x;
  const int CH = (N + 1023) / 1024;
  int s0 = t * CH, s1 = s0 + CH; if (s1 > N) s1 = N;
  int s = 0;
  for (int i = s0; i < s1; ++i) s += cnt[i];
  sums[t] = s;
  __syncthreads();
  for (int d = 1; d < 1024; d <<= 1) {
    int v = sums[t];
    int u = (t >= d) ? sums[t - d] : 0;
    __syncthreads();
    sums[t] = v + u;
    __syncthreads();
  }
  int run = (t == 0) ? 0 : sums[t - 1];
  for (int i = s0; i < s1; ++i) { rowptr[i] = run; run += cnt[i]; }
  if (t == 1023) rowptr[N] = sums[1023];
}

__global__ void scatter_kernel(const int* __restrict__ dst, const int* __restrict__ src,
                               const int* __restrict__ rowptr, int* __restrict__ fill,
                               int* __restrict__ srcs, int E) {
  int e = blockIdx.x * 256 + threadIdx.x;
  if (e >= E) return;
  int d = dst[e];
  int pos = atomicAdd(&fill[d], 1);
  srcs[rowptr[d] + pos] = src[e];
}

// ==== aggx: per dst node, xagg[n,h,:] = sum_e alpha_e,h * xb[src_e,:] ========
// Pass 1 roles: (head=lane>>3, j=lane&7). Agg roles: group g=lane>>4 owns edge
// slots g,g+4,...; lane l15 owns dims [l15*8, l15*8+8) (one uint4 gather).
__global__ __launch_bounds__(256)
void aggx_kernel(const unsigned short* __restrict__ xb,
                 const float* __restrict__ el, const float* __restrict__ er,
                 const int* __restrict__ srcs, const int* __restrict__ rowptr,
                 unsigned short* __restrict__ xagg, int N) {
  __shared__ float wlds[4][64 * 8];
  __shared__ int slds[4][64];
  __shared__ float mzlds[4][16];
  int wv = threadIdx.x >> 6;
  int n = blockIdx.x * 4 + wv;
  if (n >= N) return;
  int lane = threadIdx.x & 63;
  const int myh = lane >> 3, j = lane & 7;
  const int g = lane >> 4, l15 = lane & 15;
  int p0 = rowptr[n], p1 = rowptr[n + 1];
  int deg = p1 - p0;
  float* wl = wlds[wv];
  int* sd = slds[wv];
  float* mz = mzlds[wv];
  float acc[8][8] = {};   // [head][dim], static-indexed only
  if (deg > 0) {
    float er8[8];
    *(float4*)&er8[0] = *(const float4*)(er + (size_t)n * 8);
    *(float4*)&er8[4] = *(const float4*)(er + (size_t)n * 8 + 4);
    float erh = er8[0];
    #pragma unroll
    for (int h = 1; h < 8; ++h) erh = (myh == h) ? er8[h] : erh;
    // pass 1: softmax stats (m, 1/z) per head
    float m = -3.4e38f;
    for (int i = p0 + j; i < p1; i += 8)
      m = fmaxf(m, lrelu(el[(size_t)srcs[i] * 8 + myh] + erh));
    m = fmaxf(m, __shfl_xor(m, 1));
    m = fmaxf(m, __shfl_xor(m, 2));
    m = fmaxf(m, __shfl_xor(m, 4));
    float z = 0.f;
    for (int i = p0 + j; i < p1; i += 8)
      z += __expf(lrelu(el[(size_t)srcs[i] * 8 + myh] + erh) - m);
    z += __shfl_xor(z, 1); z += __shfl_xor(z, 2); z += __shfl_xor(z, 4);
    if (j == 0) { mz[myh] = m; mz[8 + myh] = 1.f / z; }
    asm volatile("s_waitcnt lgkmcnt(0)" ::: "memory");
    float m8[8], iz8[8];
    #pragma unroll
    for (int h = 0; h < 8; ++h) { m8[h] = mz[h]; iz8[h] = mz[8 + h]; }
    // chunks of 64 edges
    for (int c0 = p0; c0 < p1; c0 += 64) {
      int cnt = min(64, p1 - c0);
      if (lane < cnt) {
        int s = srcs[c0 + lane];
        sd[lane] = s;
        float elr[8];
        *(float4*)&elr[0] = *(const float4*)(el + (size_t)s * 8);
        *(float4*)&elr[4] = *(const float4*)(el + (size_t)s * 8 + 4);
        #pragma unroll
        for (int h = 0; h < 8; ++h)
          wl[lane * 8 + h] = __expf(lrelu(elr[h] + er8[h]) - m8[h]) * iz8[h];
      }
      asm volatile("s_waitcnt lgkmcnt(0)" ::: "memory");
      // 4 edges in flight: group g takes slots g, g+4, ...
      for (int t = g; t < cnt; t += 4) {
        int s = sd[t];
        uint4 u = *(const uint4*)(xb + (size_t)s * 128 + l15 * 8);
        float xd[8];
        #pragma unroll
        for (int q = 0; q < 4; ++q) {
          unsigned v = ((const unsigned*)&u)[q];
          xd[2 * q]     = __uint_as_float(v << 16);
          xd[2 * q + 1] = __uint_as_float(v & 0xFFFF0000u);
        }
        float w8[8];
        *(float4*)&w8[0] = *(const float4*)&wl[t * 8];
        *(float4*)&w8[4] = *(const float4*)&wl[t * 8 + 4];
        #pragma unroll
        for (int h = 0; h < 8; ++h)
          #pragma unroll
          for (int d = 0; d < 8; ++d)
            acc[h][d] = fmaf(w8[h], xd[d], acc[h][d]);
      }
      asm volatile("s_waitcnt lgkmcnt(0)" ::: "memory");
    }
  }
  // cross-group reduction (all lanes end with full sums)
  #pragma unroll
  for (int h = 0; h < 8; ++h)
    #pragma unroll
    for (int d = 0; d < 8; ++d) {
      float v = acc[h][d];
      v += __shfl_xor(v, 16);
      v += __shfl_xor(v, 32);
      acc[h][d] = v;
    }
  if (g == 0) {
    unsigned short* op = xagg + (size_t)n * 1024 + l15 * 8;
    #pragma unroll
    for (int h = 0; h < 8; ++h) {
      unsigned short us[8];
      #pragma unroll
      for (int d = 0; d < 8; ++d) us[d] = f2bf(acc[h][d]);
      *(uint4*)(op + h * 128) = *(const uint4*)us;
    }
  }
}

// ===== gemm1b: out1e[:, h*64:+64] = elu(xagg[:,h,:] @ W1_h + b1_h), bf16 =====
// grid (391, 8). BM=128 BN=64 BK=64, 4 waves stacked M, 2x4 frags, K=128.
__global__ __launch_bounds__(256)
void gemm1b_mfma(const unsigned short* __restrict__ A,     // xagg [NN][8][128]
                 const unsigned short* __restrict__ w1t,   // [512][128]
                 const float* __restrict__ bias,           // b1 [512]
                 unsigned short* __restrict__ out) {       // out1e [NN][512]
  __shared__ unsigned short As[128][72];
  __shared__ unsigned short Bs[64][72];
  const int t = threadIdx.x, lane = t & 63, wid = t >> 6;
  const int h = blockIdx.y;
  const int row0 = blockIdx.x * 128;
  const int l15 = lane & 15, kg = lane >> 4;
  f32x4 acc[2][4] = {};
  for (int kk = 0; kk < 128; kk += 64) {
    #pragma unroll
    for (int it = 0; it < 4; ++it) {
      int c = t + it * 256;                 // 1024 chunks A
      int r = c >> 3, kc = (c & 7) * 8;
      uint4 v = make_uint4(0, 0, 0, 0);
      if (row0 + r < NN)
        v = *(const uint4*)(A + (size_t)(row0 + r) * 1024 + h * 128 + kk + kc);
      *(uint4*)&As[r][kc] = v;
    }
    #pragma unroll
    for (int it = 0; it < 2; ++it) {
      int c = t + it * 256;                 // 512 chunks B
      int r = c >> 3, kc = (c & 7) * 8;
      *(uint4*)&Bs[r][kc] = *(const uint4*)(w1t + (size_t)(h * 64 + r) * 128 + kk + kc);
    }
    __syncthreads();
    #pragma unroll
    for (int ks = 0; ks < 2; ++ks) {
      bf16x8 af[2], bfr[4];
      #pragma unroll
      for (int fi = 0; fi < 2; ++fi)
        af[fi] = *(const bf16x8*)&As[wid * 32 + fi * 16 + l15][ks * 32 + kg * 8];
      #pragma unroll
      for (int fj = 0; fj < 4; ++fj)
        bfr[fj] = *(const bf16x8*)&Bs[fj * 16 + l15][ks * 32 + kg * 8];
      #pragma unroll
      for (int fi = 0; fi < 2; ++fi)
        #pragma unroll
        for (int fj = 0; fj < 4; ++fj)
          acc[fi][fj] = __builtin_amdgcn_mfma_f32_16x16x32_bf16(af[fi], bfr[fj], acc[fi][fj], 0, 0, 0);
    }
    __syncthreads();
  }
  float bj[4];
  #pragma unroll
  for (int fj = 0; fj < 4; ++fj) bj[fj] = bias[h * 64 + fj * 16 + l15];
  #pragma unroll
  for (int fi = 0; fi < 2; ++fi) {
    const int rbase = row0 + wid * 32 + fi * 16 + kg * 4;
    #pragma unroll
    for (int r = 0; r < 4; ++r) {
      int row = rbase + r;
      if (row < NN) {
        #pragma unroll
        for (int fj = 0; fj < 4; ++fj)
          out[(size_t)row * 512 + h * 64 + fj * 16 + l15] = f2bf(elu(acc[fi][fj][r] + bj[fj]));
      }
    }
  }
}

// ====== GEMM2 (MFMA): feat2(f32) = out1e @ W2T^T, fused el2/er2 ==============
__global__ __launch_bounds__(256)
void gemm2_mfma(const unsigned short* __restrict__ A,     // out1e [NN][512] bf16
                const unsigned short* __restrict__ w2t,   // [64][512] bf16
                const float* __restrict__ al, const float* __restrict__ ar,
                float* __restrict__ C,                    // feat2 [NN][64] f32
                float* __restrict__ el, float* __restrict__ er) {
  __shared__ unsigned short As[128][72];
  __shared__ unsigned short Bs[64][72];
  const int t = threadIdx.x, lane = t & 63, wid = t >> 6;
  const int row0 = blockIdx.x * 128;
  const int l15 = lane & 15, kg = lane >> 4;
  f32x4 acc[2][4] = {};
  for (int kk = 0; kk < 512; kk += 64) {
    #pragma unroll
    for (int it = 0; it < 4; ++it) {
      int c = t + it * 256;
      int r = c >> 3, kc = (c & 7) * 8;
      uint4 v = make_uint4(0, 0, 0, 0);
      if (row0 + r < NN) v = *(const uint4*)(A + (size_t)(row0 + r) * 512 + kk + kc);
      *(uint4*)&As[r][kc] = v;
    }
    #pragma unroll
    for (int it = 0; it < 2; ++it) {
      int c = t + it * 256;
      int r = c >> 3, kc = (c & 7) * 8;
      *(uint4*)&Bs[r][kc] = *(const uint4*)(w2t + (size_t)r * 512 + kk + kc);
    }
    __syncthreads();
    #pragma unroll
    for (int ks = 0; ks < 2; ++ks) {
      bf16x8 af[2], bfr[4];
      #pragma unroll
      for (int fi = 0; fi < 2; ++fi)
        af[fi] = *(const bf16x8*)&As[wid * 32 + fi * 16 + l15][ks * 32 + kg * 8];
      #pragma unroll
      for (int fj = 0; fj < 4; ++fj)
        bfr[fj] = *(const bf16x8*)&Bs[fj * 16 + l15][ks * 32 + kg * 8];
      #pragma unroll
      for (int fi = 0; fi < 2; ++fi)
        #pragma unroll
        for (int fj = 0; fj < 4; ++fj)
          acc[fi][fj] = __builtin_amdgcn_mfma_f32_16x16x32_bf16(af[fi], bfr[fj], acc[fi][fj], 0, 0, 0);
    }
    __syncthreads();
  }
  float alf[4], arf[4];
  #pragma unroll
  for (int fj = 0; fj < 4; ++fj) { alf[fj] = al[fj * 16 + l15]; arf[fj] = ar[fj * 16 + l15]; }
  #pragma unroll
  for (int fi = 0; fi < 2; ++fi) {
    float pl[4] = {}, pr[4] = {};
    #pragma unroll
    for (int fj = 0; fj < 4; ++fj)
      #pragma unroll
      for (int r = 0; r < 4; ++r) {
        pl[r] = fmaf(acc[fi][fj][r], alf[fj], pl[r]);
        pr[r] = fmaf(acc[fi][fj][r], arf[fj], pr[r]);
      }
    const int rbase = row0 + wid * 32 + fi * 16 + kg * 4;
    #pragma unroll
    for (int r = 0; r < 4; ++r) {
      int row = rbase + r;
      if (row < NN) {
        #pragma unroll
        for (int fj = 0; fj < 4; ++fj) C[(size_t)row * 64 + fj * 16 + l15] = acc[fi][fj][r];
      }
    }
    #pragma unroll
    for (int s = 1; s <= 8; s <<= 1)
      #pragma unroll
      for (int r = 0; r < 4; ++r) {
        pl[r] += __shfl_xor(pl[r], s);
        pr[r] += __shfl_xor(pr[r], s);
      }
    if (l15 == 0) {
      #pragma unroll
      for (int r = 0; r < 4; ++r) {
        int row = rbase + r;
        if (row < NN) { el[row] = pl[r]; er[row] = pr[r]; }
      }
    }
  }
}

// ==== agg2f: fused softmax+aggregate (single head), 4 edges in flight ========
// group g=lane>>4 owns edge slots g,g+4,...; lane l15 owns dims l15*4..+4.
__global__ __launch_bounds__(256)
void agg2f_kernel(const float* __restrict__ feat,
                  const float* __restrict__ el, const float* __restrict__ er,
                  const int* __restrict__ srcs, const int* __restrict__ rowptr,
                  const float* __restrict__ bias, float* __restrict__ out, int N) {
  __shared__ float wlds[4][256];
  __shared__ int slds[4][256];
  int wv = threadIdx.x >> 6;
  int n = blockIdx.x * 4 + wv;
  if (n >= N) return;
  int lane = threadIdx.x & 63;
  const int g = lane >> 4, l15 = lane & 15;
  int p0 = rowptr[n], p1 = rowptr[n + 1];
  int deg = p1 - p0;
  float ern = er[n];
  float* wl = wlds[wv];
  int* sd = slds[wv];
  float4 acc = make_float4(0.f, 0.f, 0.f, 0.f);
  if (deg > 0 && deg <= 256) {
    float ev[4]; int sv[4];
    float m = -3.4e38f;
    #pragma unroll
    for (int st = 0; st < 4; ++st) {
      int i = p0 + st * 64 + lane;
      float e = -3.4e38f;
      int s = 0;
      if (i < p1) { s = srcs[i]; e = lrelu(el[s] + ern); }
      sv[st] = s; ev[st] = e; m = fmaxf(m, e);
    }
    #pragma unroll
    for (int s = 1; s <= 32; s <<= 1) m = fmaxf(m, __shfl_xor(m, s));
    float z = 0.f;
    #pragma unroll
    for (int st = 0; st < 4; ++st) { ev[st] = __expf(ev[st] - m); z += ev[st]; }
    #pragma unroll
    for (int s = 1; s <= 32; s <<= 1) z += __shfl_xor(z, s);
    float iz = 1.f / z;
    #pragma unroll
    for (int st = 0; st < 4; ++st) {
      int i = p0 + st * 64 + lane;
      if (i < p1) { wl[st * 64 + lane] = ev[st] * iz; sd[st * 64 + lane] = sv[st]; }
    }
    asm volatile("s_waitcnt lgkmcnt(0)" ::: "memory");
    for (int t = g; t < deg; t += 4) {
      int s = sd[t];
      float4 f = *(const float4*)(feat + (size_t)s * 64 + l15 * 4);
      float w = wl[t];
      acc.x = fmaf(f.x, w, acc.x); acc.y = fmaf(f.y, w, acc.y);
      acc.z = fmaf(f.z, w, acc.z); acc.w = fmaf(f.w, w, acc.w);
    }
  } else if (deg > 256) {
    float m = -3.4e38f;
    for (int i = p0 + lane; i < p1; i += 64)
      m = fmaxf(m, lrelu(el[srcs[i]] + ern));
    #pragma unroll
    for (int s = 1; s <= 32; s <<= 1) m = fmaxf(m, __shfl_xor(m, s));
    float z = 0.f;
    for (int i = p0 + lane; i < p1; i += 64)
      z += __expf(lrelu(el[srcs[i]] + ern) - m);
    #pragma unroll
    for (int s = 1; s <= 32; s <<= 1) z += __shfl_xor(z, s);
    float iz = 1.f / z;
    for (int t = p0 + g; t < p1; t += 4) {
      int s = srcs[t];
      float w = __expf(lrelu(el[s] + ern) - m) * iz;
      float4 f = *(const float4*)(feat + (size_t)s * 64 + l15 * 4);
      acc.x = fmaf(f.x, w, acc.x); acc.y = fmaf(f.y, w, acc.y);
      acc.z = fmaf(f.z, w, acc.z); acc.w = fmaf(f.w, w, acc.w);
    }
  }
  // cross-group reduction
  #pragma unroll
  for (int s = 16; s <= 32; s <<= 1) {
    acc.x += __shfl_xor(acc.x, s);
    acc.y += __shfl_xor(acc.y, s);
    acc.z += __shfl_xor(acc.z, s);
    acc.w += __shfl_xor(acc.w, s);
  }
  if (g == 0) {
    float4 b = *(const float4*)(bias + l15 * 4);
    acc.x += b.x; acc.y += b.y; acc.z += b.z; acc.w += b.w;
    *(float4*)(out + (size_t)n * 64 + l15 * 4) = acc;
  }
}

extern "C" void kernel_launch(void* const* d_in, const int* in_sizes, int n_in,
                              void* d_out, int out_size, void* d_ws, size_t ws_size,
                              hipStream_t stream) {
  const float* x   = (const float*)d_in[0];
  const int*   src = (const int*)d_in[1];
  const int*   dst = (const int*)d_in[2];
  const float* W1  = (const float*)d_in[3];
  const float* al1 = (const float*)d_in[4];
  const float* ar1 = (const float*)d_in[5];
  const float* b1  = (const float*)d_in[6];
  const float* W2  = (const float*)d_in[7];
  const float* al2 = (const float*)d_in[8];
  const float* ar2 = (const float*)d_in[9];
  const float* b2  = (const float*)d_in[10];
  float* out = (float*)d_out;

  char* p = (char*)d_ws;
  auto alloc = [&](size_t bytes) { void* r = (void*)p; p += (bytes + 255) & ~(size_t)255; return r; };
  unsigned short* xb    = (unsigned short*)alloc((size_t)NN * 128 * 2);   // 12.8 MB
  unsigned short* w1t   = (unsigned short*)alloc((size_t)512 * 128 * 2);
  unsigned short* w2t   = (unsigned short*)alloc((size_t)64 * 512 * 2);
  unsigned short* walb  = (unsigned short*)alloc((size_t)16 * 128 * 2);
  unsigned short* xagg  = (unsigned short*)alloc((size_t)NN * 1024 * 2);  // 102.4 MB
  unsigned short* out1e = (unsigned short*)alloc((size_t)NN * 512 * 2);   // 51.2 MB
  float* el1   = (float*)alloc((size_t)NN * 8 * 4);
  float* er1   = (float*)alloc((size_t)NN * 8 * 4);
  float* feat2 = (float*)alloc((size_t)NN * 64 * 4);
  float* el2   = (float*)alloc((size_t)NN * 4);
  float* er2   = (float*)alloc((size_t)NN * 4);
  int* rowptr  = (int*)alloc((size_t)(NN + 1) * 4);
  int* srcs    = (int*)alloc((size_t)NE * 4);
  int* cnt     = (int*)alloc((size_t)NN * 4);
  int* fill    = (int*)alloc((size_t)NN * 4);

  hipMemsetAsync(cnt, 0, (size_t)NN * 4, stream);
  hipMemsetAsync(fill, 0, (size_t)NN * 4, stream);

  // prep
  cvt_x_kernel<<<(NN * 128 / 8 + 255) / 256, 256, 0, stream>>>(x, xb);
  wal_kernel<<<8, 256, 0, stream>>>(W1, al1, ar1, walb);
  cvt_wt_kernel<128, 512><<<(128 * 512 + 255) / 256, 256, 0, stream>>>(W1, w1t);
  cvt_wt_kernel<512, 64><<<(512 * 64 + 255) / 256, 256, 0, stream>>>(W2, w2t);

  // CSR build
  hist_kernel<<<(NE + 255) / 256, 256, 0, stream>>>(dst, cnt, NE);
  scan_kernel<<<1, 1024, 0, stream>>>(cnt, rowptr, NN);
  scatter_kernel<<<(NE + 255) / 256, 256, 0, stream>>>(dst, src, rowptr, fill, srcs, NE);

  // layer 1 (linearity-reordered)
  eler_kernel<<<(NN + 63) / 64, 256, 0, stream>>>(xb, walb, el1, er1);
  aggx_kernel<<<(NN + 3) / 4, 256, 0, stream>>>(xb, el1, er1, srcs, rowptr, xagg, NN);
  gemm1b_mfma<<<dim3((NN + 127) / 128, 8), 256, 0, stream>>>(xagg, w1t, b1, out1e);

  // layer 2
  gemm2_mfma<<<(NN + 127) / 128, 256, 0, stream>>>(out1e, w2t, al2, ar2, feat2, el2, er2);
  agg2f_kernel<<<(NN + 3) / 4, 256, 0, stream>>>(feat2, el2, er2, srcs, rowptr, b2, out, NN);
}

// Round 10
// 369.951 us; speedup vs baseline: 1.1725x; 1.1725x over previous
//
#include <hip/hip_runtime.h>
#include <cstdint>

// GAT 2-layer: N=50000, E=800000.
// Layer 1 via linearity: aggregate x (256B bf16 rows, L2-resident), then
// batched per-head MFMA GEMM. Agg kernels: single-pass softmax (1 gather/edge
// + shfl-tree reduction) for deg<=64, which is ~all nodes (Poisson(16)).
#define NN 50000
#define NE 800000

typedef short bf16x8 __attribute__((ext_vector_type(8)));
typedef float f32x4 __attribute__((ext_vector_type(4)));

__device__ __forceinline__ float lrelu(float x) { return x > 0.f ? x : 0.2f * x; }
__device__ __forceinline__ float elu(float x) { return x > 0.f ? x : __expf(x) - 1.f; }
__device__ __forceinline__ unsigned short f2bf(float f) {
  unsigned u = __float_as_uint(f);
  unsigned r = (u + 0x7FFFu + ((u >> 16) & 1u)) >> 16;   // RNE
  return (unsigned short)r;
}

// ===================== prep =====================
__global__ __launch_bounds__(256)
void cvt_x_kernel(const float* __restrict__ in, unsigned short* __restrict__ outb) {
  int idx = blockIdx.x * 256 + threadIdx.x;      // 8 elems each
  if (idx >= NN * 128 / 8) return;
  float4 a = *(const float4*)(in + (size_t)idx * 8);
  float4 b = *(const float4*)(in + (size_t)idx * 8 + 4);
  unsigned short us[8] = { f2bf(a.x), f2bf(a.y), f2bf(a.z), f2bf(a.w),
                           f2bf(b.x), f2bf(b.y), f2bf(b.z), f2bf(b.w) };
  *(uint4*)(outb + (size_t)idx * 8) = *(const uint4*)us;
}

// W [K][N] f32 -> WT [N][K] bf16
template<int K, int N>
__global__ __launch_bounds__(256)
void cvt_wt_kernel(const float* __restrict__ w, unsigned short* __restrict__ wt) {
  int idx = blockIdx.x * 256 + threadIdx.x;
  if (idx >= K * N) return;
  int k = idx / N, c = idx % N;
  wt[(size_t)c * K + k] = f2bf(w[idx]);
}

// walb[o][k] (o: 0-7 el heads, 8-15 er heads) = sum_d W1[k, h*64+d]*a[h,d]
__global__ __launch_bounds__(256)
void wal_kernel(const float* __restrict__ W1, const float* __restrict__ al,
                const float* __restrict__ ar, unsigned short* __restrict__ walb) {
  int idx = blockIdx.x * 256 + threadIdx.x;   // 2048 total
  if (idx >= 2048) return;
  int k = idx >> 4, o = idx & 15, h = o & 7;
  const float* a = (o < 8) ? al : ar;
  float s = 0.f;
  #pragma unroll 8
  for (int d = 0; d < 64; ++d)
    s += W1[(size_t)k * 512 + h * 64 + d] * a[h * 64 + d];
  walb[o * 128 + k] = f2bf(s);
}

// ===== eler: el1/er1 [N,8] = xb @ walb^T via MFMA, 16 nodes/wave ============
__global__ __launch_bounds__(256)
void eler_kernel(const unsigned short* __restrict__ xb,    // [NN][128]
                 const unsigned short* __restrict__ walb,  // [16][128]
                 float* __restrict__ el, float* __restrict__ er) {
  int wv = threadIdx.x >> 6, lane = threadIdx.x & 63;
  int row0 = blockIdx.x * 64 + wv * 16;
  const int l15 = lane & 15, kg = lane >> 4;
  f32x4 c = {0.f, 0.f, 0.f, 0.f};
  #pragma unroll
  for (int ks = 0; ks < 4; ++ks) {
    bf16x8 a = {};
    int row = row0 + l15;
    if (row < NN) a = *(const bf16x8*)(xb + (size_t)row * 128 + ks * 32 + kg * 8);
    bf16x8 b = *(const bf16x8*)(walb + (size_t)l15 * 128 + ks * 32 + kg * 8);
    c = __builtin_amdgcn_mfma_f32_16x16x32_bf16(a, b, c, 0, 0, 0);
  }
  #pragma unroll
  for (int r = 0; r < 4; ++r) {
    int row = row0 + kg * 4 + r;
    if (row < NN) {
      if (l15 < 8) el[(size_t)row * 8 + l15] = c[r];
      else         er[(size_t)row * 8 + (l15 - 8)] = c[r];
    }
  }
}

// ===================== CSR build (by dst) ====================================
__global__ void hist_kernel(const int* __restrict__ dst, int* __restrict__ cnt, int E) {
  int e = blockIdx.x * 256 + threadIdx.x;
  if (e < E) atomicAdd(&cnt[dst[e]], 1);
}

__global__ __launch_bounds__(1024)
void scan_kernel(const int* __restrict__ cnt, int* __restrict__ rowptr, int N) {
  __shared__ int sums[1024];
  int t = threadIdx.x;
  const int CH = (N + 1023) / 1024;
  int s0 = t * CH, s1 = s0 + CH; if (s1 > N) s1 = N;
  int s = 0;
  for (int i = s0; i < s1; ++i) s += cnt[i];
  sums[t] = s;
  __syncthreads();
  for (int d = 1; d < 1024; d <<= 1) {
    int v = sums[t];
    int u = (t >= d) ? sums[t - d] : 0;
    __syncthreads();
    sums[t] = v + u;
    __syncthreads();
  }
  int run = (t == 0) ? 0 : sums[t - 1];
  for (int i = s0; i < s1; ++i) { rowptr[i] = run; run += cnt[i]; }
  if (t == 1023) rowptr[N] = sums[1023];
}

__global__ void scatter_kernel(const int* __restrict__ dst, const int* __restrict__ src,
                               const int* __restrict__ rowptr, int* __restrict__ fill,
                               int* __restrict__ srcs, int E) {
  int e = blockIdx.x * 256 + threadIdx.x;
  if (e >= E) return;
  int d = dst[e];
  int pos = atomicAdd(&fill[d], 1);
  srcs[rowptr[d] + pos] = src[e];
}

// ==== aggx: per dst node, xagg[n,h,:] = sum_e alpha_e,h * xb[src_e,:] ========
// deg<=64 fast path: lane l stages edge l (ONE 32B el-gather), m/z for all 8
// heads via 6-step shfl_xor tree, weights+srcs -> LDS, then agg loop where
// lane owns dims {2*lane, 2*lane+1} (4B gather/edge/lane, round-8 layout).
__global__ __launch_bounds__(256)
void aggx_kernel(const unsigned short* __restrict__ xb,
                 const float* __restrict__ el, const float* __restrict__ er,
                 const int* __restrict__ srcs, const int* __restrict__ rowptr,
                 unsigned short* __restrict__ xagg, int N) {
  __shared__ float wlds[4][64 * 8];
  __shared__ int slds[4][64];
  __shared__ float mzlds[4][16];
  int wv = threadIdx.x >> 6;
  int n = blockIdx.x * 4 + wv;
  if (n >= N) return;
  int lane = threadIdx.x & 63;
  const int myh = lane >> 3, j = lane & 7;
  int p0 = rowptr[n], p1 = rowptr[n + 1];
  int deg = p1 - p0;
  float* wl = wlds[wv];
  int* sd = slds[wv];
  float acc[16] = {};
  if (deg > 0) {
    float er8[8];
    *(float4*)&er8[0] = *(const float4*)(er + (size_t)n * 8);
    *(float4*)&er8[4] = *(const float4*)(er + (size_t)n * 8 + 4);
    if (deg <= 64) {
      // ---- single-pass stats ----
      float e8[8];
      int s = 0;
      if (lane < deg) {
        s = srcs[p0 + lane];
        float elr[8];
        *(float4*)&elr[0] = *(const float4*)(el + (size_t)s * 8);
        *(float4*)&elr[4] = *(const float4*)(el + (size_t)s * 8 + 4);
        #pragma unroll
        for (int h = 0; h < 8; ++h) e8[h] = lrelu(elr[h] + er8[h]);
      } else {
        #pragma unroll
        for (int h = 0; h < 8; ++h) e8[h] = -3.4e38f;
      }
      float m8[8];
      #pragma unroll
      for (int h = 0; h < 8; ++h) m8[h] = e8[h];
      #pragma unroll
      for (int st = 1; st <= 32; st <<= 1)
        #pragma unroll
        for (int h = 0; h < 8; ++h) m8[h] = fmaxf(m8[h], __shfl_xor(m8[h], st));
      float w8[8], z8[8];
      #pragma unroll
      for (int h = 0; h < 8; ++h) {
        w8[h] = (lane < deg) ? __expf(e8[h] - m8[h]) : 0.f;
        z8[h] = w8[h];
      }
      #pragma unroll
      for (int st = 1; st <= 32; st <<= 1)
        #pragma unroll
        for (int h = 0; h < 8; ++h) z8[h] += __shfl_xor(z8[h], st);
      if (lane < deg) {
        sd[lane] = s;
        #pragma unroll
        for (int h = 0; h < 8; ++h) wl[lane * 8 + h] = w8[h] * (1.f / z8[h]);
      }
      asm volatile("s_waitcnt lgkmcnt(0)" ::: "memory");
      // ---- aggregation ----
      for (int i = 0; i < deg; ++i) {
        int s2 = sd[i];
        unsigned u = *(const unsigned*)(xb + (size_t)s2 * 128 + lane * 2);
        float lo = __uint_as_float(u << 16);
        float hi = __uint_as_float(u & 0xFFFF0000u);
        float4 wa = *(const float4*)&wl[i * 8];
        float4 wb = *(const float4*)&wl[i * 8 + 4];
        acc[0]  = fmaf(wa.x, lo, acc[0]);  acc[1]  = fmaf(wa.x, hi, acc[1]);
        acc[2]  = fmaf(wa.y, lo, acc[2]);  acc[3]  = fmaf(wa.y, hi, acc[3]);
        acc[4]  = fmaf(wa.z, lo, acc[4]);  acc[5]  = fmaf(wa.z, hi, acc[5]);
        acc[6]  = fmaf(wa.w, lo, acc[6]);  acc[7]  = fmaf(wa.w, hi, acc[7]);
        acc[8]  = fmaf(wb.x, lo, acc[8]);  acc[9]  = fmaf(wb.x, hi, acc[9]);
        acc[10] = fmaf(wb.y, lo, acc[10]); acc[11] = fmaf(wb.y, hi, acc[11]);
        acc[12] = fmaf(wb.z, lo, acc[12]); acc[13] = fmaf(wb.z, hi, acc[13]);
        acc[14] = fmaf(wb.w, lo, acc[14]); acc[15] = fmaf(wb.w, hi, acc[15]);
      }
    } else {
      // ---- fallback (deg>64): 3-pass, chunked (round-8 code) ----
      float* mz = mzlds[wv];
      float erh = er8[0];
      #pragma unroll
      for (int h = 1; h < 8; ++h) erh = (myh == h) ? er8[h] : erh;
      float m = -3.4e38f;
      for (int i = p0 + j; i < p1; i += 8)
        m = fmaxf(m, lrelu(el[(size_t)srcs[i] * 8 + myh] + erh));
      m = fmaxf(m, __shfl_xor(m, 1));
      m = fmaxf(m, __shfl_xor(m, 2));
      m = fmaxf(m, __shfl_xor(m, 4));
      float z = 0.f;
      for (int i = p0 + j; i < p1; i += 8)
        z += __expf(lrelu(el[(size_t)srcs[i] * 8 + myh] + erh) - m);
      z += __shfl_xor(z, 1); z += __shfl_xor(z, 2); z += __shfl_xor(z, 4);
      if (j == 0) { mz[myh] = m; mz[8 + myh] = 1.f / z; }
      asm volatile("s_waitcnt lgkmcnt(0)" ::: "memory");
      float m8[8], iz8[8];
      #pragma unroll
      for (int h = 0; h < 8; ++h) { m8[h] = mz[h]; iz8[h] = mz[8 + h]; }
      for (int c0 = p0; c0 < p1; c0 += 64) {
        int cnt = min(64, p1 - c0);
        if (lane < cnt) {
          int s = srcs[c0 + lane];
          sd[lane] = s;
          float elr[8];
          *(float4*)&elr[0] = *(const float4*)(el + (size_t)s * 8);
          *(float4*)&elr[4] = *(const float4*)(el + (size_t)s * 8 + 4);
          #pragma unroll
          for (int h = 0; h < 8; ++h)
            wl[lane * 8 + h] = __expf(lrelu(elr[h] + er8[h]) - m8[h]) * iz8[h];
        }
        asm volatile("s_waitcnt lgkmcnt(0)" ::: "memory");
        for (int i = 0; i < cnt; ++i) {
          int s2 = sd[i];
          unsigned u = *(const unsigned*)(xb + (size_t)s2 * 128 + lane * 2);
          float lo = __uint_as_float(u << 16);
          float hi = __uint_as_float(u & 0xFFFF0000u);
          float4 wa = *(const float4*)&wl[i * 8];
          float4 wb = *(const float4*)&wl[i * 8 + 4];
          acc[0]  = fmaf(wa.x, lo, acc[0]);  acc[1]  = fmaf(wa.x, hi, acc[1]);
          acc[2]  = fmaf(wa.y, lo, acc[2]);  acc[3]  = fmaf(wa.y, hi, acc[3]);
          acc[4]  = fmaf(wa.z, lo, acc[4]);  acc[5]  = fmaf(wa.z, hi, acc[5]);
          acc[6]  = fmaf(wa.w, lo, acc[6]);  acc[7]  = fmaf(wa.w, hi, acc[7]);
          acc[8]  = fmaf(wb.x, lo, acc[8]);  acc[9]  = fmaf(wb.x, hi, acc[9]);
          acc[10] = fmaf(wb.y, lo, acc[10]); acc[11] = fmaf(wb.y, hi, acc[11]);
          acc[12] = fmaf(wb.z, lo, acc[12]); acc[13] = fmaf(wb.z, hi, acc[13]);
          acc[14] = fmaf(wb.w, lo, acc[14]); acc[15] = fmaf(wb.w, hi, acc[15]);
        }
        asm volatile("s_waitcnt lgkmcnt(0)" ::: "memory");
      }
    }
  }
  unsigned short* op = xagg + (size_t)n * 1024;
  #pragma unroll
  for (int h = 0; h < 8; ++h) {
    unsigned pk = (unsigned)f2bf(acc[2 * h]) | ((unsigned)f2bf(acc[2 * h + 1]) << 16);
    *(unsigned*)(op + h * 128 + lane * 2) = pk;
  }
}

// ===== gemm1b: out1e[:, h*64:+64] = elu(xagg[:,h,:] @ W1_h + b1_h), bf16 =====
// grid (391, 8). BM=128 BN=64 BK=64, 4 waves stacked M, 2x4 frags, K=128.
__global__ __launch_bounds__(256)
void gemm1b_mfma(const unsigned short* __restrict__ A,     // xagg [NN][8][128]
                 const unsigned short* __restrict__ w1t,   // [512][128]
                 const float* __restrict__ bias,           // b1 [512]
                 unsigned short* __restrict__ out) {       // out1e [NN][512]
  __shared__ unsigned short As[128][72];
  __shared__ unsigned short Bs[64][72];
  const int t = threadIdx.x, lane = t & 63, wid = t >> 6;
  const int h = blockIdx.y;
  const int row0 = blockIdx.x * 128;
  const int l15 = lane & 15, kg = lane >> 4;
  f32x4 acc[2][4] = {};
  for (int kk = 0; kk < 128; kk += 64) {
    #pragma unroll
    for (int it = 0; it < 4; ++it) {
      int c = t + it * 256;                 // 1024 chunks A
      int r = c >> 3, kc = (c & 7) * 8;
      uint4 v = make_uint4(0, 0, 0, 0);
      if (row0 + r < NN)
        v = *(const uint4*)(A + (size_t)(row0 + r) * 1024 + h * 128 + kk + kc);
      *(uint4*)&As[r][kc] = v;
    }
    #pragma unroll
    for (int it = 0; it < 2; ++it) {
      int c = t + it * 256;                 // 512 chunks B
      int r = c >> 3, kc = (c & 7) * 8;
      *(uint4*)&Bs[r][kc] = *(const uint4*)(w1t + (size_t)(h * 64 + r) * 128 + kk + kc);
    }
    __syncthreads();
    #pragma unroll
    for (int ks = 0; ks < 2; ++ks) {
      bf16x8 af[2], bfr[4];
      #pragma unroll
      for (int fi = 0; fi < 2; ++fi)
        af[fi] = *(const bf16x8*)&As[wid * 32 + fi * 16 + l15][ks * 32 + kg * 8];
      #pragma unroll
      for (int fj = 0; fj < 4; ++fj)
        bfr[fj] = *(const bf16x8*)&Bs[fj * 16 + l15][ks * 32 + kg * 8];
      #pragma unroll
      for (int fi = 0; fi < 2; ++fi)
        #pragma unroll
        for (int fj = 0; fj < 4; ++fj)
          acc[fi][fj] = __builtin_amdgcn_mfma_f32_16x16x32_bf16(af[fi], bfr[fj], acc[fi][fj], 0, 0, 0);
    }
    __syncthreads();
  }
  float bj[4];
  #pragma unroll
  for (int fj = 0; fj < 4; ++fj) bj[fj] = bias[h * 64 + fj * 16 + l15];
  #pragma unroll
  for (int fi = 0; fi < 2; ++fi) {
    const int rbase = row0 + wid * 32 + fi * 16 + kg * 4;
    #pragma unroll
    for (int r = 0; r < 4; ++r) {
      int row = rbase + r;
      if (row < NN) {
        #pragma unroll
        for (int fj = 0; fj < 4; ++fj)
          out[(size_t)row * 512 + h * 64 + fj * 16 + l15] = f2bf(elu(acc[fi][fj][r] + bj[fj]));
      }
    }
  }
}

// ====== GEMM2 (MFMA): feat2(f32) = out1e @ W2T^T, fused el2/er2 ==============
__global__ __launch_bounds__(256)
void gemm2_mfma(const unsigned short* __restrict__ A,     // out1e [NN][512] bf16
                const unsigned short* __restrict__ w2t,   // [64][512] bf16
                const float* __restrict__ al, const float* __restrict__ ar,
                float* __restrict__ C,                    // feat2 [NN][64] f32
                float* __restrict__ el, float* __restrict__ er) {
  __shared__ unsigned short As[128][72];
  __shared__ unsigned short Bs[64][72];
  const int t = threadIdx.x, lane = t & 63, wid = t >> 6;
  const int row0 = blockIdx.x * 128;
  const int l15 = lane & 15, kg = lane >> 4;
  f32x4 acc[2][4] = {};
  for (int kk = 0; kk < 512; kk += 64) {
    #pragma unroll
    for (int it = 0; it < 4; ++it) {
      int c = t + it * 256;
      int r = c >> 3, kc = (c & 7) * 8;
      uint4 v = make_uint4(0, 0, 0, 0);
      if (row0 + r < NN) v = *(const uint4*)(A + (size_t)(row0 + r) * 512 + kk + kc);
      *(uint4*)&As[r][kc] = v;
    }
    #pragma unroll
    for (int it = 0; it < 2; ++it) {
      int c = t + it * 256;
      int r = c >> 3, kc = (c & 7) * 8;
      *(uint4*)&Bs[r][kc] = *(const uint4*)(w2t + (size_t)r * 512 + kk + kc);
    }
    __syncthreads();
    #pragma unroll
    for (int ks = 0; ks < 2; ++ks) {
      bf16x8 af[2], bfr[4];
      #pragma unroll
      for (int fi = 0; fi < 2; ++fi)
        af[fi] = *(const bf16x8*)&As[wid * 32 + fi * 16 + l15][ks * 32 + kg * 8];
      #pragma unroll
      for (int fj = 0; fj < 4; ++fj)
        bfr[fj] = *(const bf16x8*)&Bs[fj * 16 + l15][ks * 32 + kg * 8];
      #pragma unroll
      for (int fi = 0; fi < 2; ++fi)
        #pragma unroll
        for (int fj = 0; fj < 4; ++fj)
          acc[fi][fj] = __builtin_amdgcn_mfma_f32_16x16x32_bf16(af[fi], bfr[fj], acc[fi][fj], 0, 0, 0);
    }
    __syncthreads();
  }
  float alf[4], arf[4];
  #pragma unroll
  for (int fj = 0; fj < 4; ++fj) { alf[fj] = al[fj * 16 + l15]; arf[fj] = ar[fj * 16 + l15]; }
  #pragma unroll
  for (int fi = 0; fi < 2; ++fi) {
    float pl[4] = {}, pr[4] = {};
    #pragma unroll
    for (int fj = 0; fj < 4; ++fj)
      #pragma unroll
      for (int r = 0; r < 4; ++r) {
        pl[r] = fmaf(acc[fi][fj][r], alf[fj], pl[r]);
        pr[r] = fmaf(acc[fi][fj][r], arf[fj], pr[r]);
      }
    const int rbase = row0 + wid * 32 + fi * 16 + kg * 4;
    #pragma unroll
    for (int r = 0; r < 4; ++r) {
      int row = rbase + r;
      if (row < NN) {
        #pragma unroll
        for (int fj = 0; fj < 4; ++fj) C[(size_t)row * 64 + fj * 16 + l15] = acc[fi][fj][r];
      }
    }
    #pragma unroll
    for (int s = 1; s <= 8; s <<= 1)
      #pragma unroll
      for (int r = 0; r < 4; ++r) {
        pl[r] += __shfl_xor(pl[r], s);
        pr[r] += __shfl_xor(pr[r], s);
      }
    if (l15 == 0) {
      #pragma unroll
      for (int r = 0; r < 4; ++r) {
        int row = rbase + r;
        if (row < NN) { el[row] = pl[r]; er[row] = pr[r]; }
      }
    }
  }
}

// ==== agg2f: fused softmax+aggregate (single head), single-pass ==============
__global__ __launch_bounds__(256)
void agg2f_kernel(const float* __restrict__ feat,
                  const float* __restrict__ el, const float* __restrict__ er,
                  const int* __restrict__ srcs, const int* __restrict__ rowptr,
                  const float* __restrict__ bias, float* __restrict__ out, int N) {
  __shared__ float wlds[4][64];
  __shared__ int slds[4][64];
  int wv = threadIdx.x >> 6;
  int n = blockIdx.x * 4 + wv;
  if (n >= N) return;
  int lane = threadIdx.x & 63;
  int p0 = rowptr[n], p1 = rowptr[n + 1];
  int deg = p1 - p0;
  float ern = er[n];
  float* wl = wlds[wv];
  int* sd = slds[wv];
  float acc = 0.f;
  if (deg > 0 && deg <= 64) {
    int s = 0;
    float e = -3.4e38f;
    if (lane < deg) { s = srcs[p0 + lane]; e = lrelu(el[s] + ern); }
    float m = e;
    #pragma unroll
    for (int st = 1; st <= 32; st <<= 1) m = fmaxf(m, __shfl_xor(m, st));
    float w = (lane < deg) ? __expf(e - m) : 0.f;
    float z = w;
    #pragma unroll
    for (int st = 1; st <= 32; st <<= 1) z += __shfl_xor(z, st);
    if (lane < deg) { wl[lane] = w * (1.f / z); sd[lane] = s; }
    asm volatile("s_waitcnt lgkmcnt(0)" ::: "memory");
    for (int i = 0; i < deg; ++i)
      acc = fmaf(feat[(size_t)sd[i] * 64 + lane], wl[i], acc);
  } else if (deg > 64) {
    float m = -3.4e38f;
    for (int i = p0 + lane; i < p1; i += 64)
      m = fmaxf(m, lrelu(el[srcs[i]] + ern));
    #pragma unroll
    for (int st = 1; st <= 32; st <<= 1) m = fmaxf(m, __shfl_xor(m, st));
    float z = 0.f;
    for (int i = p0 + lane; i < p1; i += 64)
      z += __expf(lrelu(el[srcs[i]] + ern) - m);
    #pragma unroll
    for (int st = 1; st <= 32; st <<= 1) z += __shfl_xor(z, st);
    float iz = 1.f / z;
    for (int i = p0; i < p1; ++i) {
      int s0 = srcs[i];
      float w = __expf(lrelu(el[s0] + ern) - m) * iz;
      acc = fmaf(feat[(size_t)s0 * 64 + lane], w, acc);
    }
  }
  out[(size_t)n * 64 + lane] = acc + bias[lane];
}

extern "C" void kernel_launch(void* const* d_in, const int* in_sizes, int n_in,
                              void* d_out, int out_size, void* d_ws, size_t ws_size,
                              hipStream_t stream) {
  const float* x   = (const float*)d_in[0];
  const int*   src = (const int*)d_in[1];
  const int*   dst = (const int*)d_in[2];
  const float* W1  = (const float*)d_in[3];
  const float* al1 = (const float*)d_in[4];
  const float* ar1 = (const float*)d_in[5];
  const float* b1  = (const float*)d_in[6];
  const float* W2  = (const float*)d_in[7];
  const float* al2 = (const float*)d_in[8];
  const float* ar2 = (const float*)d_in[9];
  const float* b2  = (const float*)d_in[10];
  float* out = (float*)d_out;

  char* p = (char*)d_ws;
  auto alloc = [&](size_t bytes) { void* r = (void*)p; p += (bytes + 255) & ~(size_t)255; return r; };
  unsigned short* xb    = (unsigned short*)alloc((size_t)NN * 128 * 2);   // 12.8 MB
  unsigned short* w1t   = (unsigned short*)alloc((size_t)512 * 128 * 2);
  unsigned short* w2t   = (unsigned short*)alloc((size_t)64 * 512 * 2);
  unsigned short* walb  = (unsigned short*)alloc((size_t)16 * 128 * 2);
  unsigned short* xagg  = (unsigned short*)alloc((size_t)NN * 1024 * 2);  // 102.4 MB
  unsigned short* out1e = (unsigned short*)alloc((size_t)NN * 512 * 2);   // 51.2 MB
  float* el1   = (float*)alloc((size_t)NN * 8 * 4);
  float* er1   = (float*)alloc((size_t)NN * 8 * 4);
  float* feat2 = (float*)alloc((size_t)NN * 64 * 4);
  float* el2   = (float*)alloc((size_t)NN * 4);
  float* er2   = (float*)alloc((size_t)NN * 4);
  int* rowptr  = (int*)alloc((size_t)(NN + 1) * 4);
  int* srcs    = (int*)alloc((size_t)NE * 4);
  int* cnt     = (int*)alloc((size_t)NN * 4);
  int* fill    = (int*)alloc((size_t)NN * 4);

  hipMemsetAsync(cnt, 0, (size_t)NN * 4, stream);
  hipMemsetAsync(fill, 0, (size_t)NN * 4, stream);

  // prep
  cvt_x_kernel<<<(NN * 128 / 8 + 255) / 256, 256, 0, stream>>>(x, xb);
  wal_kernel<<<8, 256, 0, stream>>>(W1, al1, ar1, walb);
  cvt_wt_kernel<128, 512><<<(128 * 512 + 255) / 256, 256, 0, stream>>>(W1, w1t);
  cvt_wt_kernel<512, 64><<<(512 * 64 + 255) / 256, 256, 0, stream>>>(W2, w2t);

  // CSR build
  hist_kernel<<<(NE + 255) / 256, 256, 0, stream>>>(dst, cnt, NE);
  scan_kernel<<<1, 1024, 0, stream>>>(cnt, rowptr, NN);
  scatter_kernel<<<(NE + 255) / 256, 256, 0, stream>>>(dst, src, rowptr, fill, srcs, NE);

  // layer 1 (linearity-reordered)
  eler_kernel<<<(NN + 63) / 64, 256, 0, stream>>>(xb, walb, el1, er1);
  aggx_kernel<<<(NN + 3) / 4, 256, 0, stream>>>(xb, el1, er1, srcs, rowptr, xagg, NN);
  gemm1b_mfma<<<dim3((NN + 127) / 128, 8), 256, 0, stream>>>(xagg, w1t, b1, out1e);

  // layer 2
  gemm2_mfma<<<(NN + 127) / 128, 256, 0, stream>>>(out1e, w2t, al2, ar2, feat2, el2, er2);
  agg2f_kernel<<<(NN + 3) / 4, 256, 0, stream>>>(feat2, el2, er2, srcs, rowptr, b2, out, NN);
}